// Round 1
// baseline (44.574 us; speedup 1.0000x reference)
//
#include <hip/hip_runtime.h>
#include <hip/hip_fp16.h>
#include <math.h>

// Quantizer LAC path: per-row max/min -> sigmoid-scaled clip -> symmetric
// int4 quantization. x: [R=8192, D=4096] fp32. Outputs: q (fp32, same shape)
// then per-row scales (fp16 values, stored as fp32 in d_out) concatenated.

#define DIM 4096
#define TPB 256
// floats per thread = DIM / TPB = 16 (4 x float4)

__global__ __launch_bounds__(TPB) void quant_rows(
    const float* __restrict__ x,
    const float* __restrict__ cmax_p,
    const float* __restrict__ cmin_p,
    float* __restrict__ qout,
    float* __restrict__ sout)
{
    const int row = blockIdx.x;
    const size_t base = (size_t)row * DIM;
    const float4* __restrict__ xr = (const float4*)(x + base);
    float4*       __restrict__ qr = (float4*)(qout + base);
    const int t = threadIdx.x;

    // ---- load row into registers, tracking max/min ----
    float4 v[4];
    float mx = -INFINITY;
    float mn =  INFINITY;
#pragma unroll
    for (int k = 0; k < 4; ++k) {
        v[k] = xr[t + k * TPB];
        mx = fmaxf(mx, fmaxf(fmaxf(v[k].x, v[k].y), fmaxf(v[k].z, v[k].w)));
        mn = fminf(mn, fminf(fminf(v[k].x, v[k].y), fminf(v[k].z, v[k].w)));
    }

    // ---- wave64 butterfly reduction ----
#pragma unroll
    for (int off = 32; off >= 1; off >>= 1) {
        mx = fmaxf(mx, __shfl_xor(mx, off));
        mn = fminf(mn, __shfl_xor(mn, off));
    }

    // ---- cross-wave (4 waves) via LDS ----
    __shared__ float smx[4], smn[4];
    __shared__ float s_scale;
    const int wid = t >> 6;
    if ((t & 63) == 0) { smx[wid] = mx; smn[wid] = mn; }
    __syncthreads();

    if (t == 0) {
        float bmx = fmaxf(fmaxf(smx[0], smx[1]), fmaxf(smx[2], smx[3]));
        float bmn = fminf(fminf(smn[0], smn[1]), fminf(smn[2], smn[3]));
        // sigmoid computed in double -> correctly-rounded fp32 result
        // (matches numpy's fp32 sigmoid; avoids 1-ulp expf mismatch).
        float sgx = (float)(1.0 / (1.0 + exp(-(double)cmax_p[0])));
        float sgn = (float)(1.0 / (1.0 + exp(-(double)cmin_p[0])));
        bmx = fmaxf(bmx, 0.0f) * sgx;          // xmax = max(xmax,0)*sig
        bmn = fminf(bmn, 0.0f) * sgn;          // xmin = min(xmin,0)*sig
        float xm = fmaxf(fabsf(bmn), bmx);     // symmetric range
        float sc = (xm == 0.0f) ? 1.0f : (xm / 7.0f);   // fp32 division, like ref
        float scf = __half2float(__float2half(sc));     // fp16 RNE round-trip
        s_scale = scf;
        sout[row] = scf;                       // scales chunk (read back as f32)
    }
    __syncthreads();

    const float s = s_scale;
    // ---- quantize from registers: rint(x/s) clamped to [-8, 7] ----
    // NOTE: must be true IEEE fp32 division (no rcp) so rint matches numpy.
#pragma unroll
    for (int k = 0; k < 4; ++k) {
        float4 o;
        o.x = fminf(fmaxf(rintf(v[k].x / s), -8.0f), 7.0f);
        o.y = fminf(fmaxf(rintf(v[k].y / s), -8.0f), 7.0f);
        o.z = fminf(fmaxf(rintf(v[k].z / s), -8.0f), 7.0f);
        o.w = fminf(fmaxf(rintf(v[k].w / s), -8.0f), 7.0f);
        qr[t + k * TPB] = o;
    }
}

extern "C" void kernel_launch(void* const* d_in, const int* in_sizes, int n_in,
                              void* d_out, int out_size, void* d_ws, size_t ws_size,
                              hipStream_t stream) {
    const float* x    = (const float*)d_in[0];
    const float* cmax = (const float*)d_in[1];
    const float* cmin = (const float*)d_in[2];
    float* out = (float*)d_out;

    const int nq   = in_sizes[0];        // 2*4096*4096
    const int rows = nq / DIM;           // 8192
    float* sout = out + (size_t)nq;      // scales chunk follows q chunk

    quant_rows<<<rows, TPB, 0, stream>>>(x, cmax, cmin, out, sout);
}